// Round 22
// baseline (294.293 us; speedup 1.0000x reference)
//
#include <hip/hip_runtime.h>
#include <hip/hip_bf16.h>
#include <stdint.h>

#define E_NUM 16
#define T_NUM 8192
#define H_DIM 1024
#define I_DIM 4096
#define MPE   512   // tokens per expert

typedef __attribute__((ext_vector_type(8))) short short8;
typedef __attribute__((ext_vector_type(4))) float f32x4;
using bf16 = __hip_bfloat16;

typedef const __attribute__((address_space(1))) void GLV;
typedef __attribute__((address_space(3))) void LDSV;

__device__ __forceinline__ uint32_t pack2_bf16(float a, float b) {
  union { float f; uint32_t u; } ua, ub;
  ua.f = a; ub.f = b;
  uint32_t x = ua.u + (0x7FFFu + ((ua.u >> 16) & 1u));
  uint32_t y = ub.u + (0x7FFFu + ((ub.u >> 16) & 1u));
  return (x >> 16) | (y & 0xFFFF0000u);
}

// two float4 -> uint4 of 8 bf16 (RNE, v_cvt_pk_bf16_f32)
__device__ __forceinline__ uint4 cvt8u(float4 a, float4 b) {
  union { uint4 u; __hip_bfloat162 h[4]; } r;
  r.h[0] = __float22bfloat162_rn({a.x, a.y});
  r.h[1] = __float22bfloat162_rn({a.z, a.w});
  r.h[2] = __float22bfloat162_rn({b.x, b.y});
  r.h[3] = __float22bfloat162_rn({b.z, b.w});
  return r.u;
}

// fast GELU (validated R10-R21: absmax unchanged at 0.03125)
__device__ __forceinline__ float fast_gelu(float x) {
  const float p = x * fmaf(x * x, -0.0713548162726f, -1.59576912161f);
  return x * __builtin_amdgcn_rcpf(1.0f + __expf(p));
}

// ---------------- gather + cast: xp[r] = bf16(hs[perm[r]]) ----------------
__global__ __launch_bounds__(256)
void gather_cast_kernel(const float* __restrict__ hs, const int* __restrict__ perm,
                        uint32_t* __restrict__ xp) {
  const int r = blockIdx.x;
  const int t = threadIdx.x;
  const int src = perm[r];
  float4 v = ((const float4*)(hs + (size_t)src * H_DIM))[t];
  uint2 o;
  o.x = pack2_bf16(v.x, v.y);
  o.y = pack2_bf16(v.z, v.w);
  ((uint2*)(xp + (size_t)r * (H_DIM / 2)))[t] = o;
}

// -- grouped GEMM: BM=256/BN=128/BK=32, 512 thr, bf16-B, TRIPLE-BUF counted --
// C = A(bf16,[E][512][KFULL]) * B(f32,[E][N][KFULL])^T over K window.
// R21's kernel (2 blocks/CU proven) + R16's counted pipeline: 3 LDS buffers
// (72 KB; 2x72=144 <= 160 KB, 2x512 threads <= 2048 -> still 2 blocks/CU),
// stage(t+2) issued at top of iter t, vmcnt(4) retires ALL of t+1 while
// t+2's 4 VMEM ops stay in flight -- never a full drain in steady state.
// B regs: two named sets, parity rotation (R17-validated, rule-#20 safe).
//   A: [128 lds-rows][64] bf16 pair-packed (R13/R21-validated geometry)
//   B: [64][64] bf16 pair-packed (R18/R19/R21-validated pack)
// EPI=1: gelu -> bf16 Hout, LDS-coalesced (2 passes of 128 rows).
// EPI=0: f32 partial to Pout (split-K).
template<int EPI, int KSPLIT, int N, int KFULL, int KLEN, int LOG_NBN>
__global__ __launch_bounds__(512, 2)
void moe_gemm_kernel(const bf16* __restrict__ A, const float* __restrict__ Bw,
                     const float* __restrict__ bias, bf16* __restrict__ Hout,
                     float* __restrict__ Pout) {
  constexpr int NK = KLEN / 32;
  __shared__ bf16 As[3][256 * 32];   // 16 KB each (epilogue reuses As[0..1])
  __shared__ bf16 Bs[3][64 * 64];    // 8 KB each   (total 72 KB)

  // bijective chunked XCD swizzle (m204); nwg % 8 == 0; bm fastest -> B-panel
  // sharers adjacent -> same XCD chunk -> L2 reuse.
  const int nwg = gridDim.x, qx = nwg >> 3, orig = blockIdx.x;
  const int wg = (orig & 7) * qx + (orig >> 3);
  const int bm   = wg & 1;
  const int bn   = (wg >> 1) & ((1 << LOG_NBN) - 1);
  const int rest = wg >> (1 + LOG_NBN);
  const int ks = (KSPLIT == 2) ? (rest & 1) : 0;
  const int e  = (KSPLIT == 2) ? (rest >> 1) : rest;
  const int K0 = ks * KLEN;

  const int tid = threadIdx.x;
  const int l = tid & 63;
  const int w = tid >> 6;                  // 0..7
  const int wr = w >> 1, wc = w & 1;       // 4 M-waves x 2 N-waves
  const int fr = l & 15, fq = l >> 4;
  const int rx = fr & 7;

  const bf16*  Ae = A  + ((size_t)e * MPE + (size_t)bm * 256) * KFULL + K0;
  const float* Be = Bw + ((size_t)e * N + (size_t)bn * 128) * KFULL + K0;

  // A staging (R13/R21-validated): granule j in {tid, tid+512}: lds-row p =
  // i*64 + (tid>>3), slot s = tid&7, g = s^(p&7); real row = p + 128*(g>>2),
  // k-chunk (g&3)*8.
  const int p0 = tid >> 3;
  const int ga = (tid & 7) ^ (p0 & 7);
  const bf16* As0 = Ae + (size_t)(p0      + 128 * (ga >> 2)) * KFULL + (ga & 3) * 8;
  const bf16* As1 = Ae + (size_t)(p0 + 64 + 128 * (ga >> 2)) * KFULL + (ga & 3) * 8;

  // B staging (R21-validated): col c = tid>>2 (0..127), seg sg = tid&3
  // (8 f32 = one 16B bf16 chunk); packed row p = c&63, half h = c>>6;
  // chunk lc = h*4 + sg, phys lc^(p&7).
  const int bc = tid >> 2, bsg = tid & 3;
  const float* Bsrc = Be + (size_t)bc * KFULL + bsg * 8;
  const int bp  = bc & 63;
  const int bwo = bp * 64 + (((((bc >> 6) << 2) | bsg) ^ (bp & 7)) << 3);

  // fragment read offsets (R21-validated)
  const int aso = (((((wr >> 1) << 2)) | fq) ^ rx) * 8;
  const int bro = fr * 64 + ((((wc << 2) | fq) ^ rx) << 3);   // + n*1024

  f32x4 acc[4][4];
#pragma unroll
  for (int m = 0; m < 4; ++m)
#pragma unroll
    for (int n = 0; n < 4; ++n) acc[m][n] = (f32x4){0.f, 0.f, 0.f, 0.f};

  // two named in-flight B reg sets: B(kt) lives in set kt&1
  float4 s0a, s0b, s1a, s1b;

  // issue order: B first (2 loads), then A (2 glds)
#define ISSUE(buf, kt, d0, d1)                                                      \
  {                                                                                 \
    d0 = *(const float4*)(Bsrc + (kt) * 32);                                        \
    d1 = *(const float4*)(Bsrc + (kt) * 32 + 4);                                    \
    __builtin_amdgcn_global_load_lds((GLV*)(As0 + (kt) * 32),                       \
                                     (LDSV*)&As[buf][tid * 8], 16, 0, 0);           \
    __builtin_amdgcn_global_load_lds((GLV*)(As1 + (kt) * 32),                       \
                                     (LDSV*)&As[buf][(512 + tid) * 8], 16, 0, 0);   \
  }
#define WRITE_B(buf, r0, r1) { *(uint4*)&Bs[buf][bwo] = cvt8u(r0, r1); }

  // ---- prologue: issue tiles 0,1; retire tile 0 (tile 1 flies); publish B(0)
  ISSUE(0, 0, s0a, s0b);
  ISSUE(1, 1, s1a, s1b);
  asm volatile("s_waitcnt vmcnt(4)" ::: "memory");
  __builtin_amdgcn_sched_barrier(0);
  WRITE_B(0, s0a, s0b);
  asm volatile("s_waitcnt lgkmcnt(0)" ::: "memory");
  __builtin_amdgcn_sched_barrier(0);
  __builtin_amdgcn_s_barrier();
  __builtin_amdgcn_sched_barrier(0);

  int bufc = 0, bufn1 = 1, bufn2 = 2;
  for (int t = 0; t < NK; ++t) {
    // issue stage(t+2) into bufn2 (its readers finished before end-of-(t-1)
    // barrier); B(t+2) goes into reg set (t+2)&1 == t&1 (freed at iter t-1)
    if (t + 2 < NK) {
      if ((t & 1) == 0) { ISSUE(bufn2, t + 2, s0a, s0b); }
      else              { ISSUE(bufn2, t + 2, s1a, s1b); }
      asm volatile("s_waitcnt vmcnt(4)" ::: "memory");   // ALL of (t+1) retired
      __builtin_amdgcn_sched_barrier(0);
    } else if (t + 1 < NK) {
      asm volatile("s_waitcnt vmcnt(0)" ::: "memory");
      __builtin_amdgcn_sched_barrier(0);
    }
    // publish B(t+1) (reg set (t+1)&1) into bufn1 -- nobody reads bufn1 now
    if (t + 1 < NK) {
      if (((t + 1) & 1) == 0) { WRITE_B(bufn1, s0a, s0b); }
      else                    { WRITE_B(bufn1, s1a, s1b); }
    }

    // ---- compute tile t from bufc (one kstep of 32)
    short8 a8[4];
#pragma unroll
    for (int m = 0; m < 4; ++m)
      a8[m] = *(const short8*)&As[bufc][((wr & 1) * 64 + m * 16 + fr) * 64 + aso];
    short8 b8[4];
#pragma unroll
    for (int n = 0; n < 4; ++n)
      b8[n] = *(const short8*)&Bs[bufc][bro + n * 1024];
#pragma unroll
    for (int m = 0; m < 4; ++m)
#pragma unroll
      for (int n = 0; n < 4; ++n)
        acc[m][n] = __builtin_amdgcn_mfma_f32_16x16x32_bf16(a8[m], b8[n], acc[m][n], 0, 0, 0);

    // B-write + frag ds_reads retired; barrier; t+2's VMEM stays in flight
    asm volatile("s_waitcnt lgkmcnt(0)" ::: "memory");
    __builtin_amdgcn_sched_barrier(0);
    __builtin_amdgcn_s_barrier();
    __builtin_amdgcn_sched_barrier(0);

    const int b0 = bufc;
    bufc = bufn1; bufn1 = bufn2; bufn2 = b0;
  }
#undef ISSUE
#undef WRITE_B
  __syncthreads();   // all waves done before epilogue LDS reuse

  // ---- epilogue
  if (EPI == 1) {
    float bv[4];
#pragma unroll
    for (int n = 0; n < 4; ++n)
      bv[n] = bias[(size_t)e * N + bn * 128 + wc * 64 + n * 16 + fr];
    bf16* He = Hout + (size_t)e * MPE * N;

    // LDS-coalesced (R15/R21-validated): 2 passes of 128 rows, As[0..1] = 32 KB
    bf16* Ls = &As[0][0];
#pragma unroll
    for (int P = 0; P < 2; ++P) {
      if ((wr >> 1) == P) {
        const int wrl = wr & 1;
#pragma unroll
        for (int m = 0; m < 4; ++m) {
#pragma unroll
          for (int j = 0; j < 4; ++j) {
            const int lr = wrl * 64 + m * 16 + fq * 4 + j;   // 0..127
#pragma unroll
            for (int n = 0; n < 4; ++n) {
              const int c = wc * 64 + n * 16 + fr;           // 0..127
              const int byteoff = lr * 256 + ((c * 2) ^ ((lr & 7) << 4));
              Ls[byteoff >> 1] = __float2bfloat16(fast_gelu(acc[m][n][j] + bv[n]));
            }
          }
        }
      }
      __syncthreads();
#pragma unroll
      for (int q = 0; q < 4; ++q) {
        const int o = (tid + q * 512) * 16;        // byte offset in 32 KB
        const int lr = o >> 8;                     // 0..127
        const int cb = o & 255;                    // byte-in-row
        const int sb = lr * 256 + (cb ^ ((lr & 7) << 4));
        uint4 v = *(const uint4*)((const char*)Ls + sb);
        *(uint4*)&He[(size_t)(bm * 256 + P * 128 + lr) * N + bn * 128 + (cb >> 1)] = v;
      }
      __syncthreads();
    }
  } else {
    float* Pd = Pout + (size_t)ks * T_NUM * H_DIM + (size_t)e * MPE * N;
#pragma unroll
    for (int m = 0; m < 4; ++m) {
#pragma unroll
      for (int j = 0; j < 4; ++j) {
        const int row = bm * 256 + wr * 64 + m * 16 + fq * 4 + j;
#pragma unroll
        for (int n = 0; n < 4; ++n) {
          const int col = bn * 128 + wc * 64 + n * 16 + fr;
          Pd[(size_t)row * N + col] = acc[m][n][j];
        }
      }
    }
  }
}

// -------- reduce partials + bias + residual + LayerNorm + scatter ----------
__global__ __launch_bounds__(256)
void ln_resid2_kernel(float* __restrict__ out, const float* __restrict__ hs,
                      const float* __restrict__ p0, const float* __restrict__ p1,
                      const float* __restrict__ b2, const float* __restrict__ gamma,
                      const float* __restrict__ beta, const int* __restrict__ perm,
                      const int two) {
  const int r = blockIdx.x;
  const int t = threadIdx.x;
  const int e = r >> 9;
  const int drow = perm[r];
  float4 a = ((const float4*)(p0 + (size_t)r * H_DIM))[t];
  if (two) {
    float4 b = ((const float4*)(p1 + (size_t)r * H_DIM))[t];
    a.x += b.x; a.y += b.y; a.z += b.z; a.w += b.w;
  }
  float4 bb = ((const float4*)(b2 + (size_t)e * H_DIM))[t];
  float4 h  = ((const float4*)(hs + (size_t)drow * H_DIM))[t];
  float v0 = a.x + bb.x + h.x, v1 = a.y + bb.y + h.y;
  float v2 = a.z + bb.z + h.z, v3 = a.w + bb.w + h.w;
  float s  = v0 + v1 + v2 + v3;
  float sq = v0 * v0 + v1 * v1 + v2 * v2 + v3 * v3;
#pragma unroll
  for (int off = 32; off > 0; off >>= 1) {
    s  += __shfl_down(s, off);
    sq += __shfl_down(sq, off);
  }
  __shared__ float ss[4], ssq[4];
  const int wv = t >> 6;
  if ((t & 63) == 0) { ss[wv] = s; ssq[wv] = sq; }
  __syncthreads();
  s  = ss[0] + ss[1] + ss[2] + ss[3];
  sq = ssq[0] + ssq[1] + ssq[2] + ssq[3];
  const float mu  = s * (1.0f / (float)H_DIM);
  const float var = sq * (1.0f / (float)H_DIM) - mu * mu;
  const float rs  = rsqrtf(var + 1e-12f);
  float4 g = ((const float4*)gamma)[t];
  float4 b = ((const float4*)beta)[t];
  float4 rr;
  rr.x = (v0 - mu) * rs * g.x + b.x;
  rr.y = (v1 - mu) * rs * g.y + b.y;
  rr.z = (v2 - mu) * rs * g.z + b.z;
  rr.w = (v3 - mu) * rs * g.w + b.w;
  ((float4*)(out + (size_t)drow * H_DIM))[t] = rr;
}

extern "C" void kernel_launch(void* const* d_in, const int* in_sizes, int n_in,
                              void* d_out, int out_size, void* d_ws, size_t ws_size,
                              hipStream_t stream) {
  const float* hs    = (const float*)d_in[0];
  const int*   perm  = (const int*)d_in[1];
  const float* w1    = (const float*)d_in[2];
  const float* b1    = (const float*)d_in[3];
  const float* w2    = (const float*)d_in[4];
  const float* b2    = (const float*)d_in[5];
  const float* gamma = (const float*)d_in[6];
  const float* beta  = (const float*)d_in[7];
  float* out = (float*)d_out;

  const size_t xp_b   = (size_t)T_NUM * H_DIM * sizeof(bf16);   // 16 MB
  const size_t hbuf_b = (size_t)T_NUM * I_DIM * sizeof(bf16);   // 64 MB
  const size_t part_b = (size_t)T_NUM * H_DIM * sizeof(float);  // 32 MB each

  bf16*  xp   = (bf16*)d_ws;
  bf16*  hbuf = (bf16*)((char*)d_ws + xp_b);
  float* pbuf = (float*)((char*)d_ws + xp_b + hbuf_b);

  gather_cast_kernel<<<T_NUM, 256, 0, stream>>>(hs, perm, (uint32_t*)xp);

  // GEMM1: BM=256, grid = 2 bm x 32 bn x 16 e = 1024 blocks (2/CU resident)
  moe_gemm_kernel<1, 1, I_DIM, H_DIM, H_DIM, 5>
      <<<1024, 512, 0, stream>>>(xp, w1, b1, hbuf, nullptr);

  if (ws_size >= xp_b + hbuf_b + 2 * part_b) {
    // GEMM2 split-K=2: grid = 2 bm x 8 bn x 2 ks x 16 e = 512 (2/CU)
    moe_gemm_kernel<0, 2, H_DIM, I_DIM, I_DIM / 2, 3>
        <<<512, 512, 0, stream>>>(hbuf, w2, nullptr, nullptr, pbuf);
    ln_resid2_kernel<<<T_NUM, 256, 0, stream>>>(out, hs, pbuf, pbuf + (size_t)T_NUM * H_DIM,
                                                b2, gamma, beta, perm, 1);
  } else {
    moe_gemm_kernel<0, 1, H_DIM, I_DIM, I_DIM, 3>
        <<<256, 512, 0, stream>>>(hbuf, w2, nullptr, nullptr, pbuf);
    ln_resid2_kernel<<<T_NUM, 256, 0, stream>>>(out, hs, pbuf, nullptr,
                                                b2, gamma, beta, perm, 0);
  }
}

// Round 23
// 275.292 us; speedup vs baseline: 1.0690x; 1.0690x over previous
//
#include <hip/hip_runtime.h>
#include <hip/hip_bf16.h>
#include <stdint.h>

#define E_NUM 16
#define T_NUM 8192
#define H_DIM 1024
#define I_DIM 4096
#define MPE   512   // tokens per expert

typedef __attribute__((ext_vector_type(8))) short short8;
typedef __attribute__((ext_vector_type(4))) float f32x4;
using bf16 = __hip_bfloat16;

typedef const __attribute__((address_space(1))) void GLV;
typedef __attribute__((address_space(3))) void LDSV;

__device__ __forceinline__ uint32_t pack2_bf16(float a, float b) {
  union { float f; uint32_t u; } ua, ub;
  ua.f = a; ub.f = b;
  uint32_t x = ua.u + (0x7FFFu + ((ua.u >> 16) & 1u));
  uint32_t y = ub.u + (0x7FFFu + ((ub.u >> 16) & 1u));
  return (x >> 16) | (y & 0xFFFF0000u);
}

// two float4 -> uint4 of 8 bf16 (RNE, v_cvt_pk_bf16_f32)
__device__ __forceinline__ uint4 cvt8u(float4 a, float4 b) {
  union { uint4 u; __hip_bfloat162 h[4]; } r;
  r.h[0] = __float22bfloat162_rn({a.x, a.y});
  r.h[1] = __float22bfloat162_rn({a.z, a.w});
  r.h[2] = __float22bfloat162_rn({b.x, b.y});
  r.h[3] = __float22bfloat162_rn({b.z, b.w});
  return r.u;
}

// fast GELU (validated R10-R22: absmax unchanged at 0.03125)
__device__ __forceinline__ float fast_gelu(float x) {
  const float p = x * fmaf(x * x, -0.0713548162726f, -1.59576912161f);
  return x * __builtin_amdgcn_rcpf(1.0f + __expf(p));
}

// ---------------- gather + cast: xp[r] = bf16(hs[perm[r]]) ----------------
__global__ __launch_bounds__(256)
void gather_cast_kernel(const float* __restrict__ hs, const int* __restrict__ perm,
                        uint32_t* __restrict__ xp) {
  const int r = blockIdx.x;
  const int t = threadIdx.x;
  const int src = perm[r];
  float4 v = ((const float4*)(hs + (size_t)src * H_DIM))[t];
  uint2 o;
  o.x = pack2_bf16(v.x, v.y);
  o.y = pack2_bf16(v.z, v.w);
  ((uint2*)(xp + (size_t)r * (H_DIM / 2)))[t] = o;
}

// --- grouped GEMM: BM=256/BN=128/BK=32, 512 thr, bf16-B, 40 KB -> 2 blk/CU --
// C = A(bf16,[E][512][KFULL]) * B(f32,[E][N][KFULL])^T over K window.
// R21-verbatim (275.9 us best): dbuf bf16-B, B-first issue, vmcnt(2) publish,
// one drain+barrier per iter; 512-thread blocks co-reside 2/CU so the partner
// block's compute hides the drain (m114).  8 waves (4M x 2N), per-wave 64x64.
//   A: [128 lds-rows][64] bf16 pair-packed dbuf (R13-validated geometry)
//   B: [64][64] bf16 pair-packed dbuf (R18/R19-validated pack)
// EPI=1: gelu -> bf16 Hout, LDS-coalesced (2 passes of 128 rows).
// EPI=0: f32 partial to Pout (split-K).
template<int EPI, int KSPLIT, int N, int KFULL, int KLEN, int LOG_NBN>
__global__ __launch_bounds__(512, 2)
void moe_gemm_kernel(const bf16* __restrict__ A, const float* __restrict__ Bw,
                     const float* __restrict__ bias, bf16* __restrict__ Hout,
                     float* __restrict__ Pout) {
  constexpr int NK = KLEN / 32;
  __shared__ bf16 As[2][256 * 32];   // 16 KB each (epilogue reuses both)
  __shared__ bf16 Bs[2][64 * 64];    // 8 KB each   (total 40 KB)

  // bijective chunked XCD swizzle (m204); nwg % 8 == 0; bm fastest so the two
  // B-panel sharers are adjacent -> same XCD chunk -> L2 reuse.
  const int nwg = gridDim.x, qx = nwg >> 3, orig = blockIdx.x;
  const int wg = (orig & 7) * qx + (orig >> 3);
  const int bm   = wg & 1;
  const int bn   = (wg >> 1) & ((1 << LOG_NBN) - 1);
  const int rest = wg >> (1 + LOG_NBN);
  const int ks = (KSPLIT == 2) ? (rest & 1) : 0;
  const int e  = (KSPLIT == 2) ? (rest >> 1) : rest;
  const int K0 = ks * KLEN;

  const int tid = threadIdx.x;
  const int l = tid & 63;
  const int w = tid >> 6;                  // 0..7
  const int wr = w >> 1, wc = w & 1;       // 4 M-waves x 2 N-waves
  const int fr = l & 15, fq = l >> 4;
  const int rx = fr & 7;

  const bf16*  Ae = A  + ((size_t)e * MPE + (size_t)bm * 256) * KFULL + K0;
  const float* Be = Bw + ((size_t)e * N + (size_t)bn * 128) * KFULL + K0;

  // A staging (R13-validated): granule j in {tid, tid+512}: lds-row p =
  // i*64 + (tid>>3), slot s = tid&7, g = s^(p&7); real row = p + 128*(g>>2),
  // k-chunk (g&3)*8.
  const int p0 = tid >> 3;
  const int ga = (tid & 7) ^ (p0 & 7);
  const bf16* As0 = Ae + (size_t)(p0      + 128 * (ga >> 2)) * KFULL + (ga & 3) * 8;
  const bf16* As1 = Ae + (size_t)(p0 + 64 + 128 * (ga >> 2)) * KFULL + (ga & 3) * 8;

  // B staging (R18/R19 pack, 512-thr variant): col c = tid>>2 (0..127),
  // seg sg = tid&3 (8 f32 = one 16B bf16 chunk); packed row p = c&63,
  // half h = c>>6; chunk lc = h*4 + sg, phys lc^(p&7).
  const int bc = tid >> 2, bsg = tid & 3;
  const float* Bsrc = Be + (size_t)bc * KFULL + bsg * 8;
  const int bp  = bc & 63;
  const int bwo = bp * 64 + (((((bc >> 6) << 2) | bsg) ^ (bp & 7)) << 3);

  // fragment read offsets
  const int aso = (((((wr >> 1) << 2)) | fq) ^ rx) * 8;
  const int bro = fr * 64 + ((((wc << 2) | fq) ^ rx) << 3);   // + n*1024

  f32x4 acc[4][4];
#pragma unroll
  for (int m = 0; m < 4; ++m)
#pragma unroll
    for (int n = 0; n < 4; ++n) acc[m][n] = (f32x4){0.f, 0.f, 0.f, 0.f};

  float4 br0, br1;

  // issue order: B first (2 loads), then A (2 glds) -> vmcnt(2) == B landed
#define ISSUE(buf, kt)                                                              \
  {                                                                                 \
    br0 = *(const float4*)(Bsrc + (kt) * 32);                                       \
    br1 = *(const float4*)(Bsrc + (kt) * 32 + 4);                                   \
    __builtin_amdgcn_global_load_lds((GLV*)(As0 + (kt) * 32),                       \
                                     (LDSV*)&As[buf][tid * 8], 16, 0, 0);           \
    __builtin_amdgcn_global_load_lds((GLV*)(As1 + (kt) * 32),                       \
                                     (LDSV*)&As[buf][(512 + tid) * 8], 16, 0, 0);   \
  }
#define WRITE_B(buf) { *(uint4*)&Bs[buf][bwo] = cvt8u(br0, br1); }

  // ---- prologue: stage tile 0 fully
  ISSUE(0, 0);
  asm volatile("s_waitcnt vmcnt(2)" ::: "memory");
  __builtin_amdgcn_sched_barrier(0);
  WRITE_B(0);
  asm volatile("s_waitcnt vmcnt(0) lgkmcnt(0)" ::: "memory");
  __builtin_amdgcn_sched_barrier(0);
  __builtin_amdgcn_s_barrier();
  __builtin_amdgcn_sched_barrier(0);

  for (int t = 0; t < NK; ++t) {
    const int cur = t & 1, nxt = cur ^ 1;
    const bool more = (t + 1) < NK;

    if (more) ISSUE(nxt, t + 1);   // 4 VMEM ops fly across the compute

    // ---- compute tile t (one kstep of 32)
    short8 a8[4];
#pragma unroll
    for (int m = 0; m < 4; ++m)
      a8[m] = *(const short8*)&As[cur][((wr & 1) * 64 + m * 16 + fr) * 64 + aso];
    short8 b8[4];
#pragma unroll
    for (int n = 0; n < 4; ++n)
      b8[n] = *(const short8*)&Bs[cur][bro + n * 1024];
#pragma unroll
    for (int m = 0; m < 4; ++m)
#pragma unroll
      for (int n = 0; n < 4; ++n)
        acc[m][n] = __builtin_amdgcn_mfma_f32_16x16x32_bf16(a8[m], b8[n], acc[m][n], 0, 0, 0);

    if (more) {
      // B(t+1) regs landed (2 A-glds may still be out); publish into nxt
      asm volatile("s_waitcnt vmcnt(2)" ::: "memory");
      __builtin_amdgcn_sched_barrier(0);
      WRITE_B(nxt);
      // drain A(t+1) glds + ds ops; partner block's compute hides this
      asm volatile("s_waitcnt vmcnt(0) lgkmcnt(0)" ::: "memory");
      __builtin_amdgcn_sched_barrier(0);
      __builtin_amdgcn_s_barrier();
      __builtin_amdgcn_sched_barrier(0);
    }
  }
#undef ISSUE
#undef WRITE_B
  __syncthreads();   // all waves done before epilogue LDS reuse

  // ---- epilogue
  if (EPI == 1) {
    float bv[4];
#pragma unroll
    for (int n = 0; n < 4; ++n)
      bv[n] = bias[(size_t)e * N + bn * 128 + wc * 64 + n * 16 + fr];
    bf16* He = Hout + (size_t)e * MPE * N;

    // LDS-coalesced (R15 pattern): 2 passes of 128 rows through As[0..1] (32 KB)
    bf16* Ls = &As[0][0];
#pragma unroll
    for (int P = 0; P < 2; ++P) {
      if ((wr >> 1) == P) {
        const int wrl = wr & 1;
#pragma unroll
        for (int m = 0; m < 4; ++m) {
#pragma unroll
          for (int j = 0; j < 4; ++j) {
            const int lr = wrl * 64 + m * 16 + fq * 4 + j;   // 0..127
#pragma unroll
            for (int n = 0; n < 4; ++n) {
              const int c = wc * 64 + n * 16 + fr;           // 0..127
              const int byteoff = lr * 256 + ((c * 2) ^ ((lr & 7) << 4));
              Ls[byteoff >> 1] = __float2bfloat16(fast_gelu(acc[m][n][j] + bv[n]));
            }
          }
        }
      }
      __syncthreads();
#pragma unroll
      for (int q = 0; q < 4; ++q) {
        const int o = (tid + q * 512) * 16;        // byte offset in 32 KB
        const int lr = o >> 8;                     // 0..127
        const int cb = o & 255;                    // byte-in-row
        const int sb = lr * 256 + (cb ^ ((lr & 7) << 4));
        uint4 v = *(const uint4*)((const char*)Ls + sb);
        *(uint4*)&He[(size_t)(bm * 256 + P * 128 + lr) * N + bn * 128 + (cb >> 1)] = v;
      }
      __syncthreads();
    }
  } else {
    float* Pd = Pout + (size_t)ks * T_NUM * H_DIM + (size_t)e * MPE * N;
#pragma unroll
    for (int m = 0; m < 4; ++m) {
#pragma unroll
      for (int j = 0; j < 4; ++j) {
        const int row = bm * 256 + wr * 64 + m * 16 + fq * 4 + j;
#pragma unroll
        for (int n = 0; n < 4; ++n) {
          const int col = bn * 128 + wc * 64 + n * 16 + fr;
          Pd[(size_t)row * N + col] = acc[m][n][j];
        }
      }
    }
  }
}

// -------- reduce partials + bias + residual + LayerNorm + scatter ----------
__global__ __launch_bounds__(256)
void ln_resid2_kernel(float* __restrict__ out, const float* __restrict__ hs,
                      const float* __restrict__ p0, const float* __restrict__ p1,
                      const float* __restrict__ b2, const float* __restrict__ gamma,
                      const float* __restrict__ beta, const int* __restrict__ perm,
                      const int two) {
  const int r = blockIdx.x;
  const int t = threadIdx.x;
  const int e = r >> 9;
  const int drow = perm[r];
  float4 a = ((const float4*)(p0 + (size_t)r * H_DIM))[t];
  if (two) {
    float4 b = ((const float4*)(p1 + (size_t)r * H_DIM))[t];
    a.x += b.x; a.y += b.y; a.z += b.z; a.w += b.w;
  }
  float4 bb = ((const float4*)(b2 + (size_t)e * H_DIM))[t];
  float4 h  = ((const float4*)(hs + (size_t)drow * H_DIM))[t];
  float v0 = a.x + bb.x + h.x, v1 = a.y + bb.y + h.y;
  float v2 = a.z + bb.z + h.z, v3 = a.w + bb.w + h.w;
  float s  = v0 + v1 + v2 + v3;
  float sq = v0 * v0 + v1 * v1 + v2 * v2 + v3 * v3;
#pragma unroll
  for (int off = 32; off > 0; off >>= 1) {
    s  += __shfl_down(s, off);
    sq += __shfl_down(sq, off);
  }
  __shared__ float ss[4], ssq[4];
  const int wv = t >> 6;
  if ((t & 63) == 0) { ss[wv] = s; ssq[wv] = sq; }
  __syncthreads();
  s  = ss[0] + ss[1] + ss[2] + ss[3];
  sq = ssq[0] + ssq[1] + ssq[2] + ssq[3];
  const float mu  = s * (1.0f / (float)H_DIM);
  const float var = sq * (1.0f / (float)H_DIM) - mu * mu;
  const float rs  = rsqrtf(var + 1e-12f);
  float4 g = ((const float4*)gamma)[t];
  float4 b = ((const float4*)beta)[t];
  float4 rr;
  rr.x = (v0 - mu) * rs * g.x + b.x;
  rr.y = (v1 - mu) * rs * g.y + b.y;
  rr.z = (v2 - mu) * rs * g.z + b.z;
  rr.w = (v3 - mu) * rs * g.w + b.w;
  ((float4*)(out + (size_t)drow * H_DIM))[t] = rr;
}

extern "C" void kernel_launch(void* const* d_in, const int* in_sizes, int n_in,
                              void* d_out, int out_size, void* d_ws, size_t ws_size,
                              hipStream_t stream) {
  const float* hs    = (const float*)d_in[0];
  const int*   perm  = (const int*)d_in[1];
  const float* w1    = (const float*)d_in[2];
  const float* b1    = (const float*)d_in[3];
  const float* w2    = (const float*)d_in[4];
  const float* b2    = (const float*)d_in[5];
  const float* gamma = (const float*)d_in[6];
  const float* beta  = (const float*)d_in[7];
  float* out = (float*)d_out;

  const size_t xp_b   = (size_t)T_NUM * H_DIM * sizeof(bf16);   // 16 MB
  const size_t hbuf_b = (size_t)T_NUM * I_DIM * sizeof(bf16);   // 64 MB
  const size_t part_b = (size_t)T_NUM * H_DIM * sizeof(float);  // 32 MB each

  bf16*  xp   = (bf16*)d_ws;
  bf16*  hbuf = (bf16*)((char*)d_ws + xp_b);
  float* pbuf = (float*)((char*)d_ws + xp_b + hbuf_b);

  gather_cast_kernel<<<T_NUM, 256, 0, stream>>>(hs, perm, (uint32_t*)xp);

  // GEMM1: BM=256, grid = 2 bm x 32 bn x 16 e = 1024 blocks (2/CU resident)
  moe_gemm_kernel<1, 1, I_DIM, H_DIM, H_DIM, 5>
      <<<1024, 512, 0, stream>>>(xp, w1, b1, hbuf, nullptr);

  if (ws_size >= xp_b + hbuf_b + 2 * part_b) {
    // GEMM2 split-K=2: grid = 2 bm x 8 bn x 2 ks x 16 e = 512 (2/CU)
    moe_gemm_kernel<0, 2, H_DIM, I_DIM, I_DIM / 2, 3>
        <<<512, 512, 0, stream>>>(hbuf, w2, nullptr, nullptr, pbuf);
    ln_resid2_kernel<<<T_NUM, 256, 0, stream>>>(out, hs, pbuf, pbuf + (size_t)T_NUM * H_DIM,
                                                b2, gamma, beta, perm, 1);
  } else {
    moe_gemm_kernel<0, 1, H_DIM, I_DIM, I_DIM, 3>
        <<<256, 512, 0, stream>>>(hbuf, w2, nullptr, nullptr, pbuf);
    ln_resid2_kernel<<<T_NUM, 256, 0, stream>>>(out, hs, pbuf, nullptr,
                                                b2, gamma, beta, perm, 0);
  }
}